// Round 9
// baseline (320.330 us; speedup 1.0000x reference)
//
#include <hip/hip_runtime.h>

#define N_NODES   50000
#define N_EDGES   800000
#define IN_CH     128
#define HID       64
#define N_GRAPHS  64
#define N_CLASSES 2
#define NBLK_SCAN ((N_NODES + 255) / 256)   // 196
#define NREP      32                        // pooledSum replicas
#define FILL_CHUNKS ((N_EDGES + 2047) / 2048)     // 391
#define DEG_BLOCKS (FILL_CHUNKS * 8)              // 3128

// Round 3: single-block scan 133us -> 3-phase scan.
// Round 4: pool 59us @2.3% occupancy -> atomic partial pool + finalize.
// Round 5: fill 54us (16x write amplification) -> XCD-partitioned fill.
// Round 7: agg2+pool fusion regressed (+30us, 12.5k RMW/line) -> Round 8:
// 32 pooledSum replicas fixed it (86->47us, matched prediction).
// Round 9: (a) agg gather is latency-bound (2TB/s, VALU 20%) -> 8-wide
// predicated load batches; (b) dinv-scale moved gemm1->agg1 so gemm1 is
// preproc-independent -> fused deg||gemm1 mega-kernel hides gemm1 under deg.

// ---------------------------------------------------------------------------
// K0: FUSED deg (blocks [0,DEG_BLOCKS)) || gemm1 unscaled (blocks >= DEG_BLOCKS)
// deg: XCD-partitioned dst-windowed atomic count (round-5 pattern).
// gemm1: gg1 = x @ W1 (NO dinv scale; applied per-edge in agg1).
// ---------------------------------------------------------------------------
#define FMA4(xs, w, a) { (a).x = fmaf((xs), (w).x, (a).x); \
                         (a).y = fmaf((xs), (w).y, (a).y); \
                         (a).z = fmaf((xs), (w).z, (a).z); \
                         (a).w = fmaf((xs), (w).w, (a).w); }

__global__ __launch_bounds__(256) void deg_gemm1_kernel(const int* __restrict__ ei,
                                                        int* __restrict__ degCount,
                                                        const float* __restrict__ x,
                                                        const float* __restrict__ W1,
                                                        float* __restrict__ gg) {
    __shared__ float4 Ws[IN_CH * 16];             // 32 KB (allocated for all blocks)
    if (blockIdx.x < DEG_BLOCKS) {
        // ---- degree count ----
        int part = blockIdx.x & 7;
        int blk  = blockIdx.x >> 3;               // 0..390
        int lo   = part * 6250;
        int hi   = lo + 6250;
#pragma unroll
        for (int it = 0; it < 8; ++it) {
            int e = blk * 2048 + it * 256 + (int)threadIdx.x;
            if (e < N_EDGES) {
                int dst = ei[N_EDGES + e];
                if (dst >= lo && dst < hi) atomicAdd(&degCount[dst], 1);
            }
        }
        return;
    }
    // ---- gemm1: 128 rows/block, 8 rows/thread, W1 in LDS ----
    int bid = blockIdx.x - DEG_BLOCKS;
    for (int i = threadIdx.x; i < IN_CH * 16; i += 256)
        Ws[i] = ((const float4*)W1)[i];
    __syncthreads();

    const int c4   = threadIdx.x & 15;
    const int rg   = threadIdx.x >> 4;
    const int row0 = bid * 128 + rg * 8;

    const float4* ap[8];
#pragma unroll
    for (int r = 0; r < 8; ++r) {
        int rowc = min(row0 + r, N_NODES - 1);
        ap[r] = (const float4*)(x + (size_t)rowc * IN_CH);
    }

    float4 acc[8] = {};
    for (int kk = 0; kk < IN_CH / 4; ++kk) {
        float4 xv[8];
#pragma unroll
        for (int r = 0; r < 8; ++r) xv[r] = ap[r][kk];
        float4 w;
        w = Ws[(4 * kk + 0) * 16 + c4];
#pragma unroll
        for (int r = 0; r < 8; ++r) FMA4(xv[r].x, w, acc[r]);
        w = Ws[(4 * kk + 1) * 16 + c4];
#pragma unroll
        for (int r = 0; r < 8; ++r) FMA4(xv[r].y, w, acc[r]);
        w = Ws[(4 * kk + 2) * 16 + c4];
#pragma unroll
        for (int r = 0; r < 8; ++r) FMA4(xv[r].z, w, acc[r]);
        w = Ws[(4 * kk + 3) * 16 + c4];
#pragma unroll
        for (int r = 0; r < 8; ++r) FMA4(xv[r].w, w, acc[r]);
    }

#pragma unroll
    for (int r = 0; r < 8; ++r) {
        int row = row0 + r;
        if (row < N_NODES)
            ((float4*)(gg + (size_t)row * HID))[c4] = acc[r];
    }
}

// ---------------------------------------------------------------------------
// K1a/b/c: 3-phase scan (round-3 fix)
// ---------------------------------------------------------------------------
__global__ __launch_bounds__(256) void scan1_kernel(const int* __restrict__ degCount,
                                                    int* __restrict__ blockSums) {
    __shared__ int red[256];
    int i = blockIdx.x * 256 + threadIdx.x;
    red[threadIdx.x] = (i < N_NODES) ? degCount[i] : 0;
    __syncthreads();
    for (int off = 128; off > 0; off >>= 1) {
        if (threadIdx.x < off) red[threadIdx.x] += red[threadIdx.x + off];
        __syncthreads();
    }
    if (threadIdx.x == 0) blockSums[blockIdx.x] = red[0];
}

__global__ __launch_bounds__(256) void scan2_kernel(int* __restrict__ blockSums) {
    __shared__ int s[256];
    int t = threadIdx.x;
    int v = (t < NBLK_SCAN) ? blockSums[t] : 0;
    s[t] = v;
    __syncthreads();
    for (int off = 1; off < 256; off <<= 1) {
        int a = (t >= off) ? s[t - off] : 0;
        __syncthreads();
        s[t] += a;
        __syncthreads();
    }
    if (t < NBLK_SCAN) blockSums[t] = s[t] - v;   // exclusive prefix
}

__global__ __launch_bounds__(256) void scan3_kernel(int* __restrict__ degFill,
                                                    const int* __restrict__ blockSums,
                                                    int* __restrict__ rowPtr,
                                                    float* __restrict__ dinv) {
    __shared__ int s[256];
    int t = threadIdx.x;
    int i = blockIdx.x * 256 + t;
    int d = (i < N_NODES) ? degFill[i] : 0;
    s[t] = d;
    __syncthreads();
    for (int off = 1; off < 256; off <<= 1) {
        int a = (t >= off) ? s[t - off] : 0;
        __syncthreads();
        s[t] += a;
        __syncthreads();
    }
    int excl = s[t] - d + blockSums[blockIdx.x];
    if (i < N_NODES) {
        rowPtr[i]  = excl;
        degFill[i] = excl;
        dinv[i]    = 1.0f / sqrtf((float)(d + 1));
    }
    if (i == 0) rowPtr[N_NODES] = N_EDGES;
}

// ---------------------------------------------------------------------------
// K2: CSR fill, XCD-partitioned + dst-windowed (round-5 fix).
// ---------------------------------------------------------------------------
__global__ __launch_bounds__(256) void fill_kernel(const int* __restrict__ ei,
                                                   int* __restrict__ fillPtr,
                                                   int* __restrict__ colIdx) {
    int part = blockIdx.x & 7;
    int blk  = blockIdx.x >> 3;
    int lo   = part * 6250;
    int hi   = lo + 6250;
#pragma unroll
    for (int it = 0; it < 8; ++it) {
        int e = blk * 2048 + it * 256 + (int)threadIdx.x;
        if (e < N_EDGES) {
            int dst = ei[N_EDGES + e];
            if (dst >= lo && dst < hi) {
                int src = ei[e];
                int pos = atomicAdd(&fillPtr[dst], 1);
                colIdx[pos] = src;
            }
        }
    }
}

// ---------------------------------------------------------------------------
// K5: gemm2: g2 = (h1 @ W2) * dinv[row]   (dinv folded, as before)
// ---------------------------------------------------------------------------
template <int K>
__global__ __launch_bounds__(256) void gemm_kernel(const float* __restrict__ A,
                                                   const float* __restrict__ W,
                                                   const float* __restrict__ dinv,
                                                   float* __restrict__ out) {
    __shared__ float4 Ws[K * 16];
    for (int i = threadIdx.x; i < K * 16; i += 256)
        Ws[i] = ((const float4*)W)[i];
    __syncthreads();

    const int c4   = threadIdx.x & 15;
    const int rg   = threadIdx.x >> 4;
    const int row0 = blockIdx.x * 128 + rg * 8;

    const float4* ap[8];
#pragma unroll
    for (int r = 0; r < 8; ++r) {
        int rowc = min(row0 + r, N_NODES - 1);
        ap[r] = (const float4*)(A + (size_t)rowc * K);
    }

    float4 acc[8] = {};
    for (int kk = 0; kk < K / 4; ++kk) {
        float4 xv[8];
#pragma unroll
        for (int r = 0; r < 8; ++r) xv[r] = ap[r][kk];
        float4 w;
        w = Ws[(4 * kk + 0) * 16 + c4];
#pragma unroll
        for (int r = 0; r < 8; ++r) FMA4(xv[r].x, w, acc[r]);
        w = Ws[(4 * kk + 1) * 16 + c4];
#pragma unroll
        for (int r = 0; r < 8; ++r) FMA4(xv[r].y, w, acc[r]);
        w = Ws[(4 * kk + 2) * 16 + c4];
#pragma unroll
        for (int r = 0; r < 8; ++r) FMA4(xv[r].z, w, acc[r]);
        w = Ws[(4 * kk + 3) * 16 + c4];
#pragma unroll
        for (int r = 0; r < 8; ++r) FMA4(xv[r].w, w, acc[r]);
    }

#pragma unroll
    for (int r = 0; r < 8; ++r) {
        int row = row0 + r;
        if (row < N_NODES) {
            float dv = dinv[row];
            float4 o = acc[r];
            o.x *= dv; o.y *= dv; o.z *= dv; o.w *= dv;
            ((float4*)(out + (size_t)row * HID))[c4] = o;
        }
    }
}

// ---------------------------------------------------------------------------
// K4: layer-1 aggregation over UNSCALED gg1, per-edge dinv[u] fma.
// out[v] = relu(dinv[v]*(sum du*gg[u] + dinv[v]*gg[v]) + b1)
// 8-wide predicated batches: uniform rounds, 8 outstanding loads.
// ---------------------------------------------------------------------------
__global__ __launch_bounds__(256) void agg1_kernel(const float* __restrict__ gg,
                                                   const float* __restrict__ dinv,
                                                   const int* __restrict__ rowPtr,
                                                   const int* __restrict__ colIdx,
                                                   const float* __restrict__ bias,
                                                   float* __restrict__ out) {
    int lane = threadIdx.x & 63;
    int v = blockIdx.x * 4 + (threadIdx.x >> 6);
    if (v >= N_NODES) return;

    const float dv = dinv[v];
    float accA = dv * gg[(size_t)v * HID + lane];
    float accB = 0.f;
    int e0 = rowPtr[v];
    int e1 = rowPtr[v + 1];
    for (int e = e0; e < e1; e += 8) {
        int   u[8];
        float du[8];
#pragma unroll
        for (int i = 0; i < 8; ++i) {
            int idx = min(e + i, e1 - 1);
            u[i]  = colIdx[idx];
            du[i] = (e + i < e1) ? dinv[u[i]] : 0.f;
        }
#pragma unroll
        for (int i = 0; i < 8; ++i) {
            float a = gg[(size_t)u[i] * HID + lane];
            if (i & 1) accB = fmaf(du[i], a, accB);
            else       accA = fmaf(du[i], a, accA);
        }
    }
    float r = dv * (accA + accB) + bias[lane];
    out[(size_t)v * HID + lane] = fmaxf(r, 0.f);
}

// ---------------------------------------------------------------------------
// K6: layer-2 aggregation (pre-scaled g2) fused with replicated pool atomics.
// ---------------------------------------------------------------------------
__global__ __launch_bounds__(256) void agg2pool_kernel(const float* __restrict__ g,
                                                       const float* __restrict__ dinv,
                                                       const int* __restrict__ rowPtr,
                                                       const int* __restrict__ colIdx,
                                                       const float* __restrict__ bias,
                                                       const int* __restrict__ batch,
                                                       float* __restrict__ pooledSum) {
    int lane = threadIdx.x & 63;
    int v = blockIdx.x * 4 + (threadIdx.x >> 6);
    if (v >= N_NODES) return;

    float accA = g[(size_t)v * HID + lane];
    float accB = 0.f;
    int e0 = rowPtr[v];
    int e1 = rowPtr[v + 1];
    for (int e = e0; e < e1; e += 8) {
        int   u[8];
        float wsel[8];
#pragma unroll
        for (int i = 0; i < 8; ++i) {
            int idx = min(e + i, e1 - 1);
            u[i]    = colIdx[idx];
            wsel[i] = (e + i < e1) ? 1.f : 0.f;
        }
#pragma unroll
        for (int i = 0; i < 8; ++i) {
            float a = g[(size_t)u[i] * HID + lane];
            if (i & 1) accB = fmaf(wsel[i], a, accB);
            else       accA = fmaf(wsel[i], a, accA);
        }
    }
    float r = fmaxf(dinv[v] * (accA + accB) + bias[lane], 0.f);
    int gid = batch[v];                           // wave-uniform
    int rep = blockIdx.x & (NREP - 1);
    atomicAdd(&pooledSum[(size_t)rep * N_GRAPHS * HID + gid * HID + lane], r);
}

// ---------------------------------------------------------------------------
// K7: finalize. Sums 32 replicas, divides by count, head via shuffle reduce.
// d_out layout: [ out (64x2) | pooled (64x64) ]
// ---------------------------------------------------------------------------
__global__ __launch_bounds__(64) void pool2_kernel(const float* __restrict__ pooledSum,
                                                   const int* __restrict__ batch,
                                                   const float* __restrict__ Wl,
                                                   const float* __restrict__ bl,
                                                   float* __restrict__ dout) {
    int g    = blockIdx.x;
    int lane = threadIdx.x;

    int lo0 = 0, hi = N_NODES;
    while (lo0 < hi) { int mid = (lo0 + hi) >> 1; if (batch[mid] < g) lo0 = mid + 1; else hi = mid; }
    int lo1 = lo0; hi = N_NODES;
    while (lo1 < hi) { int mid = (lo1 + hi) >> 1; if (batch[mid] < g + 1) lo1 = mid + 1; else hi = mid; }
    float cnt = (float)(lo1 - lo0);

    float s = 0.f;
#pragma unroll
    for (int rep = 0; rep < NREP; ++rep)
        s += pooledSum[(size_t)rep * N_GRAPHS * HID + g * HID + lane];

    float p = s / fmaxf(cnt, 1.0f);
    dout[N_GRAPHS * N_CLASSES + g * HID + lane] = p;

    float p0 = p * Wl[lane * N_CLASSES + 0];
    float p1 = p * Wl[lane * N_CLASSES + 1];
#pragma unroll
    for (int off = 32; off > 0; off >>= 1) {
        p0 += __shfl_down(p0, off, 64);
        p1 += __shfl_down(p1, off, 64);
    }
    if (lane == 0) {
        dout[g * N_CLASSES + 0] = p0 + bl[0];
        dout[g * N_CLASSES + 1] = p1 + bl[1];
    }
}

// ---------------------------------------------------------------------------
extern "C" void kernel_launch(void* const* d_in, const int* in_sizes, int n_in,
                              void* d_out, int out_size, void* d_ws, size_t ws_size,
                              hipStream_t stream) {
    const float* x     = (const float*)d_in[0];
    const int*   ei    = (const int*)d_in[1];    // int32 on device
    const int*   batch = (const int*)d_in[2];    // int32 on device
    const float* W1    = (const float*)d_in[3];
    const float* b1    = (const float*)d_in[4];
    const float* W2    = (const float*)d_in[5];
    const float* b2    = (const float*)d_in[6];
    const float* Wl    = (const float*)d_in[7];
    const float* bl    = (const float*)d_in[8];
    float* out = (float*)d_out;

    char* ws = (char*)d_ws;
    size_t off = 0;
    auto alloc = [&](size_t bytes) -> void* {
        void* p = ws + off;
        off += (bytes + 255) & ~(size_t)255;
        return p;
    };
    int*   degFill   = (int*)  alloc((size_t)N_NODES * 4);        // counts -> fillPtr
    int*   rowPtr    = (int*)  alloc((size_t)(N_NODES + 1) * 4);
    float* dinv      = (float*)alloc((size_t)N_NODES * 4);
    int*   blockSums = (int*)  alloc((size_t)NBLK_SCAN * 4);
    float* pooledSum = (float*)alloc((size_t)NREP * N_GRAPHS * HID * 4);  // 512 KB
    int*   colIdx    = (int*)  alloc((size_t)N_EDGES * 4);
    float* bufA      = (float*)alloc((size_t)N_NODES * HID * 4);  // gg1, then g2
    float* bufB      = (float*)alloc((size_t)N_NODES * HID * 4);  // h1

    hipMemsetAsync(degFill, 0, (size_t)N_NODES * 4, stream);
    hipMemsetAsync(pooledSum, 0, (size_t)NREP * N_GRAPHS * HID * 4, stream);

    // fused: deg (3128 blocks) || gemm1 unscaled (391 blocks)
    deg_gemm1_kernel<<<DEG_BLOCKS + (N_NODES + 127) / 128, 256, 0, stream>>>(
        ei, degFill, x, W1, bufA);
    scan1_kernel<<<NBLK_SCAN, 256, 0, stream>>>(degFill, blockSums);
    scan2_kernel<<<1, 256, 0, stream>>>(blockSums);
    scan3_kernel<<<NBLK_SCAN, 256, 0, stream>>>(degFill, blockSums, rowPtr, dinv);
    fill_kernel <<<DEG_BLOCKS, 256, 0, stream>>>(ei, degFill, colIdx);

    // layer 1 aggregation (applies dinv per-edge)
    agg1_kernel<<<N_NODES / 4, 256, 0, stream>>>(bufA, dinv, rowPtr, colIdx, b1, bufB);

    // layer 2
    gemm_kernel<HID><<<(N_NODES + 127) / 128, 256, 0, stream>>>(bufB, W2, dinv, bufA);
    agg2pool_kernel <<<N_NODES / 4, 256, 0, stream>>>(bufA, dinv, rowPtr, colIdx, b2, batch, pooledSum);

    // finalize pool + head
    pool2_kernel<<<N_GRAPHS, 64, 0, stream>>>(pooledSum, batch, Wl, bl, out);
}

// Round 10
// 290.355 us; speedup vs baseline: 1.1032x; 1.1032x over previous
//
#include <hip/hip_runtime.h>

#define N_NODES   50000
#define N_EDGES   800000
#define IN_CH     128
#define HID       64
#define N_GRAPHS  64
#define N_CLASSES 2
#define NBLK_SCAN ((N_NODES + 255) / 256)   // 196
#define NREP      32                        // pooledSum replicas
#define FILL_CHUNKS ((N_EDGES + 2047) / 2048)     // 391
#define DEG_BLOCKS (FILL_CHUNKS * 8)              // 3128

// Round 3: single-block scan 133us -> 3-phase scan.
// Round 4: pool 59us @2.3% occupancy -> atomic partial pool + finalize.
// Round 5: fill 54us (16x write amplification) -> XCD-partitioned fill.
// Round 7->8: agg2+pool fusion + 32 replicas (86->47us, matched).
// Round 9: deg||gemm1 mega-kernel REGRESSED (77us): 32KB LDS reserved by ALL
// blocks incl. 3128 LDS-free deg blocks -> 5 blocks/CU cap, latency-bound.
// Lesson: heterogeneous-role fusion shares the worst resource footprint.
// Round 10: revert fusion; keep 8-wide agg batches (clean A/B vs round-8).

// ---------------------------------------------------------------------------
// K0: in-degree count, XCD-partitioned + dst-windowed (round-5/8 form).
// ---------------------------------------------------------------------------
__global__ __launch_bounds__(256) void deg_kernel(const int* __restrict__ ei,
                                                  int* __restrict__ degCount) {
    int part = blockIdx.x & 7;
    int blk  = blockIdx.x >> 3;                   // 0..390
    int lo   = part * 6250;
    int hi   = lo + 6250;
#pragma unroll
    for (int it = 0; it < 8; ++it) {
        int e = blk * 2048 + it * 256 + (int)threadIdx.x;
        if (e < N_EDGES) {
            int dst = ei[N_EDGES + e];
            if (dst >= lo && dst < hi) atomicAdd(&degCount[dst], 1);
        }
    }
}

// ---------------------------------------------------------------------------
// K1a/b/c: 3-phase scan (round-3 fix)
// ---------------------------------------------------------------------------
__global__ __launch_bounds__(256) void scan1_kernel(const int* __restrict__ degCount,
                                                    int* __restrict__ blockSums) {
    __shared__ int red[256];
    int i = blockIdx.x * 256 + threadIdx.x;
    red[threadIdx.x] = (i < N_NODES) ? degCount[i] : 0;
    __syncthreads();
    for (int off = 128; off > 0; off >>= 1) {
        if (threadIdx.x < off) red[threadIdx.x] += red[threadIdx.x + off];
        __syncthreads();
    }
    if (threadIdx.x == 0) blockSums[blockIdx.x] = red[0];
}

__global__ __launch_bounds__(256) void scan2_kernel(int* __restrict__ blockSums) {
    __shared__ int s[256];
    int t = threadIdx.x;
    int v = (t < NBLK_SCAN) ? blockSums[t] : 0;
    s[t] = v;
    __syncthreads();
    for (int off = 1; off < 256; off <<= 1) {
        int a = (t >= off) ? s[t - off] : 0;
        __syncthreads();
        s[t] += a;
        __syncthreads();
    }
    if (t < NBLK_SCAN) blockSums[t] = s[t] - v;   // exclusive prefix
}

__global__ __launch_bounds__(256) void scan3_kernel(int* __restrict__ degFill,
                                                    const int* __restrict__ blockSums,
                                                    int* __restrict__ rowPtr,
                                                    float* __restrict__ dinv) {
    __shared__ int s[256];
    int t = threadIdx.x;
    int i = blockIdx.x * 256 + t;
    int d = (i < N_NODES) ? degFill[i] : 0;
    s[t] = d;
    __syncthreads();
    for (int off = 1; off < 256; off <<= 1) {
        int a = (t >= off) ? s[t - off] : 0;
        __syncthreads();
        s[t] += a;
        __syncthreads();
    }
    int excl = s[t] - d + blockSums[blockIdx.x];
    if (i < N_NODES) {
        rowPtr[i]  = excl;
        degFill[i] = excl;
        dinv[i]    = 1.0f / sqrtf((float)(d + 1));
    }
    if (i == 0) rowPtr[N_NODES] = N_EDGES;
}

// ---------------------------------------------------------------------------
// K2: CSR fill, XCD-partitioned + dst-windowed (round-5 fix).
// ---------------------------------------------------------------------------
__global__ __launch_bounds__(256) void fill_kernel(const int* __restrict__ ei,
                                                   int* __restrict__ fillPtr,
                                                   int* __restrict__ colIdx) {
    int part = blockIdx.x & 7;
    int blk  = blockIdx.x >> 3;
    int lo   = part * 6250;
    int hi   = lo + 6250;
#pragma unroll
    for (int it = 0; it < 8; ++it) {
        int e = blk * 2048 + it * 256 + (int)threadIdx.x;
        if (e < N_EDGES) {
            int dst = ei[N_EDGES + e];
            if (dst >= lo && dst < hi) {
                int src = ei[e];
                int pos = atomicAdd(&fillPtr[dst], 1);
                colIdx[pos] = src;
            }
        }
    }
}

// ---------------------------------------------------------------------------
// K3/K5: g = (A @ W) * dinv[row]     A:[N,K]  W:[K,64]  g:[N,64]
// Block = 256 thr = 16 col-chunks x 16 row-groups of 8 rows. W in LDS,
// LDS reads amortized 8x. (round-2 form, dinv folded)
// ---------------------------------------------------------------------------
#define FMA4(xs, w, a) { (a).x = fmaf((xs), (w).x, (a).x); \
                         (a).y = fmaf((xs), (w).y, (a).y); \
                         (a).z = fmaf((xs), (w).z, (a).z); \
                         (a).w = fmaf((xs), (w).w, (a).w); }

template <int K>
__global__ __launch_bounds__(256) void gemm_kernel(const float* __restrict__ A,
                                                   const float* __restrict__ W,
                                                   const float* __restrict__ dinv,
                                                   float* __restrict__ out) {
    __shared__ float4 Ws[K * 16];
    for (int i = threadIdx.x; i < K * 16; i += 256)
        Ws[i] = ((const float4*)W)[i];
    __syncthreads();

    const int c4   = threadIdx.x & 15;
    const int rg   = threadIdx.x >> 4;
    const int row0 = blockIdx.x * 128 + rg * 8;

    const float4* ap[8];
#pragma unroll
    for (int r = 0; r < 8; ++r) {
        int rowc = min(row0 + r, N_NODES - 1);
        ap[r] = (const float4*)(A + (size_t)rowc * K);
    }

    float4 acc[8] = {};
    for (int kk = 0; kk < K / 4; ++kk) {
        float4 xv[8];
#pragma unroll
        for (int r = 0; r < 8; ++r) xv[r] = ap[r][kk];
        float4 w;
        w = Ws[(4 * kk + 0) * 16 + c4];
#pragma unroll
        for (int r = 0; r < 8; ++r) FMA4(xv[r].x, w, acc[r]);
        w = Ws[(4 * kk + 1) * 16 + c4];
#pragma unroll
        for (int r = 0; r < 8; ++r) FMA4(xv[r].y, w, acc[r]);
        w = Ws[(4 * kk + 2) * 16 + c4];
#pragma unroll
        for (int r = 0; r < 8; ++r) FMA4(xv[r].z, w, acc[r]);
        w = Ws[(4 * kk + 3) * 16 + c4];
#pragma unroll
        for (int r = 0; r < 8; ++r) FMA4(xv[r].w, w, acc[r]);
    }

#pragma unroll
    for (int r = 0; r < 8; ++r) {
        int row = row0 + r;
        if (row < N_NODES) {
            float dv = dinv[row];
            float4 o = acc[r];
            o.x *= dv; o.y *= dv; o.z *= dv; o.w *= dv;
            ((float4*)(out + (size_t)row * HID))[c4] = o;
        }
    }
}

// ---------------------------------------------------------------------------
// K4: layer-1 aggregation (pre-scaled g), 8-wide predicated load batches.
// out[v] = relu(dinv[v]*(g[v] + sum g[u]) + bias)
// ---------------------------------------------------------------------------
__global__ __launch_bounds__(256) void agg1_kernel(const float* __restrict__ g,
                                                   const float* __restrict__ dinv,
                                                   const int* __restrict__ rowPtr,
                                                   const int* __restrict__ colIdx,
                                                   const float* __restrict__ bias,
                                                   float* __restrict__ out) {
    int lane = threadIdx.x & 63;
    int v = blockIdx.x * 4 + (threadIdx.x >> 6);
    if (v >= N_NODES) return;

    float accA = g[(size_t)v * HID + lane];
    float accB = 0.f;
    int e0 = rowPtr[v];
    int e1 = rowPtr[v + 1];
    for (int e = e0; e < e1; e += 8) {
        int   u[8];
        float wsel[8];
#pragma unroll
        for (int i = 0; i < 8; ++i) {
            int idx = min(e + i, e1 - 1);
            u[i]    = colIdx[idx];
            wsel[i] = (e + i < e1) ? 1.f : 0.f;
        }
#pragma unroll
        for (int i = 0; i < 8; ++i) {
            float a = g[(size_t)u[i] * HID + lane];
            if (i & 1) accB = fmaf(wsel[i], a, accB);
            else       accA = fmaf(wsel[i], a, accA);
        }
    }
    float r = dinv[v] * (accA + accB) + bias[lane];
    out[(size_t)v * HID + lane] = fmaxf(r, 0.f);
}

// ---------------------------------------------------------------------------
// K6: layer-2 aggregation fused with replicated pool atomics (round-8 fix),
// 8-wide predicated load batches.
// ---------------------------------------------------------------------------
__global__ __launch_bounds__(256) void agg2pool_kernel(const float* __restrict__ g,
                                                       const float* __restrict__ dinv,
                                                       const int* __restrict__ rowPtr,
                                                       const int* __restrict__ colIdx,
                                                       const float* __restrict__ bias,
                                                       const int* __restrict__ batch,
                                                       float* __restrict__ pooledSum) {
    int lane = threadIdx.x & 63;
    int v = blockIdx.x * 4 + (threadIdx.x >> 6);
    if (v >= N_NODES) return;

    float accA = g[(size_t)v * HID + lane];
    float accB = 0.f;
    int e0 = rowPtr[v];
    int e1 = rowPtr[v + 1];
    for (int e = e0; e < e1; e += 8) {
        int   u[8];
        float wsel[8];
#pragma unroll
        for (int i = 0; i < 8; ++i) {
            int idx = min(e + i, e1 - 1);
            u[i]    = colIdx[idx];
            wsel[i] = (e + i < e1) ? 1.f : 0.f;
        }
#pragma unroll
        for (int i = 0; i < 8; ++i) {
            float a = g[(size_t)u[i] * HID + lane];
            if (i & 1) accB = fmaf(wsel[i], a, accB);
            else       accA = fmaf(wsel[i], a, accA);
        }
    }
    float r = fmaxf(dinv[v] * (accA + accB) + bias[lane], 0.f);
    int gid = batch[v];                           // wave-uniform
    int rep = blockIdx.x & (NREP - 1);
    atomicAdd(&pooledSum[(size_t)rep * N_GRAPHS * HID + gid * HID + lane], r);
}

// ---------------------------------------------------------------------------
// K7: finalize. Sums 32 replicas, divides by count, head via shuffle reduce.
// d_out layout: [ out (64x2) | pooled (64x64) ]
// ---------------------------------------------------------------------------
__global__ __launch_bounds__(64) void pool2_kernel(const float* __restrict__ pooledSum,
                                                   const int* __restrict__ batch,
                                                   const float* __restrict__ Wl,
                                                   const float* __restrict__ bl,
                                                   float* __restrict__ dout) {
    int g    = blockIdx.x;
    int lane = threadIdx.x;

    int lo0 = 0, hi = N_NODES;
    while (lo0 < hi) { int mid = (lo0 + hi) >> 1; if (batch[mid] < g) lo0 = mid + 1; else hi = mid; }
    int lo1 = lo0; hi = N_NODES;
    while (lo1 < hi) { int mid = (lo1 + hi) >> 1; if (batch[mid] < g + 1) lo1 = mid + 1; else hi = mid; }
    float cnt = (float)(lo1 - lo0);

    float s = 0.f;
#pragma unroll
    for (int rep = 0; rep < NREP; ++rep)
        s += pooledSum[(size_t)rep * N_GRAPHS * HID + g * HID + lane];

    float p = s / fmaxf(cnt, 1.0f);
    dout[N_GRAPHS * N_CLASSES + g * HID + lane] = p;

    float p0 = p * Wl[lane * N_CLASSES + 0];
    float p1 = p * Wl[lane * N_CLASSES + 1];
#pragma unroll
    for (int off = 32; off > 0; off >>= 1) {
        p0 += __shfl_down(p0, off, 64);
        p1 += __shfl_down(p1, off, 64);
    }
    if (lane == 0) {
        dout[g * N_CLASSES + 0] = p0 + bl[0];
        dout[g * N_CLASSES + 1] = p1 + bl[1];
    }
}

// ---------------------------------------------------------------------------
extern "C" void kernel_launch(void* const* d_in, const int* in_sizes, int n_in,
                              void* d_out, int out_size, void* d_ws, size_t ws_size,
                              hipStream_t stream) {
    const float* x     = (const float*)d_in[0];
    const int*   ei    = (const int*)d_in[1];    // int32 on device
    const int*   batch = (const int*)d_in[2];    // int32 on device
    const float* W1    = (const float*)d_in[3];
    const float* b1    = (const float*)d_in[4];
    const float* W2    = (const float*)d_in[5];
    const float* b2    = (const float*)d_in[6];
    const float* Wl    = (const float*)d_in[7];
    const float* bl    = (const float*)d_in[8];
    float* out = (float*)d_out;

    char* ws = (char*)d_ws;
    size_t off = 0;
    auto alloc = [&](size_t bytes) -> void* {
        void* p = ws + off;
        off += (bytes + 255) & ~(size_t)255;
        return p;
    };
    int*   degFill   = (int*)  alloc((size_t)N_NODES * 4);        // counts -> fillPtr
    int*   rowPtr    = (int*)  alloc((size_t)(N_NODES + 1) * 4);
    float* dinv      = (float*)alloc((size_t)N_NODES * 4);
    int*   blockSums = (int*)  alloc((size_t)NBLK_SCAN * 4);
    float* pooledSum = (float*)alloc((size_t)NREP * N_GRAPHS * HID * 4);  // 512 KB
    int*   colIdx    = (int*)  alloc((size_t)N_EDGES * 4);
    float* bufA      = (float*)alloc((size_t)N_NODES * HID * 4);  // g1, then g2
    float* bufB      = (float*)alloc((size_t)N_NODES * HID * 4);  // h1

    hipMemsetAsync(degFill, 0, (size_t)N_NODES * 4, stream);
    hipMemsetAsync(pooledSum, 0, (size_t)NREP * N_GRAPHS * HID * 4, stream);

    deg_kernel  <<<DEG_BLOCKS, 256, 0, stream>>>(ei, degFill);
    scan1_kernel<<<NBLK_SCAN, 256, 0, stream>>>(degFill, blockSums);
    scan2_kernel<<<1, 256, 0, stream>>>(blockSums);
    scan3_kernel<<<NBLK_SCAN, 256, 0, stream>>>(degFill, blockSums, rowPtr, dinv);
    fill_kernel <<<DEG_BLOCKS, 256, 0, stream>>>(ei, degFill, colIdx);

    // layer 1: g1 = (x@W1)*dinv ; h1 = relu(dinv*(g1[v]+sum g1[u]) + b1)
    gemm_kernel<IN_CH><<<(N_NODES + 127) / 128, 256, 0, stream>>>(x, W1, dinv, bufA);
    agg1_kernel       <<<N_NODES / 4, 256, 0, stream>>>(bufA, dinv, rowPtr, colIdx, b1, bufB);

    // layer 2: g2 = (h1@W2)*dinv ; h2 row computed in-register, pooled directly
    gemm_kernel<HID><<<(N_NODES + 127) / 128, 256, 0, stream>>>(bufB, W2, dinv, bufA);
    agg2pool_kernel <<<N_NODES / 4, 256, 0, stream>>>(bufA, dinv, rowPtr, colIdx, b2, batch, pooledSum);

    // finalize pool + head
    pool2_kernel<<<N_GRAPHS, 64, 0, stream>>>(pooledSum, batch, Wl, bl, out);
}

// Round 11
// 289.186 us; speedup vs baseline: 1.1077x; 1.0040x over previous
//
#include <hip/hip_runtime.h>

#define N_NODES   50000
#define N_EDGES   800000
#define IN_CH     128
#define HID       64
#define N_GRAPHS  64
#define N_CLASSES 2
#define NBLK_SCAN ((N_NODES + 255) / 256)   // 196
#define NREP      32                        // pooledSum replicas
#define FILL_CHUNKS ((N_EDGES + 2047) / 2048)     // 391
#define DEG_BLOCKS (FILL_CHUNKS * 8)              // 3128
#define GEMM1_BLOCKS ((N_NODES + 127) / 128)      // 391

// Round 3: single-block scan 133us -> 3-phase scan.
// Round 4: pool 59us @2.3% occupancy -> atomic partial pool + finalize.
// Round 5: fill 54us (16x write amplification) -> XCD-partitioned fill.
// Round 7->8: agg2+pool fusion + 32 replicas (86->47us).
// Round 9: deg||gemm1 fusion regressed (32KB LDS reserved by ALL blocks ->
// 5 blocks/CU). Round 10: revert -> 290us; top-5 = harness ws-poison only.
// Round 11: (a) fill||gemm1 fusion with LDS-FREE gemm (W via coalesced L2
// reads) + role interleave (every 9th block = gemm) -> true co-residency;
// (b) float2 agg gathers: wave reads 2 neighbor rows/issue, halves combined
// via shfl_xor(32).

// ---------------------------------------------------------------------------
// K0: in-degree count, XCD-partitioned + dst-windowed.
// ---------------------------------------------------------------------------
__global__ __launch_bounds__(256) void deg_kernel(const int* __restrict__ ei,
                                                  int* __restrict__ degCount) {
    int part = blockIdx.x & 7;
    int blk  = blockIdx.x >> 3;                   // 0..390
    int lo   = part * 6250;
    int hi   = lo + 6250;
#pragma unroll
    for (int it = 0; it < 8; ++it) {
        int e = blk * 2048 + it * 256 + (int)threadIdx.x;
        if (e < N_EDGES) {
            int dst = ei[N_EDGES + e];
            if (dst >= lo && dst < hi) atomicAdd(&degCount[dst], 1);
        }
    }
}

// ---------------------------------------------------------------------------
// K1a/b/c: 3-phase scan
// ---------------------------------------------------------------------------
__global__ __launch_bounds__(256) void scan1_kernel(const int* __restrict__ degCount,
                                                    int* __restrict__ blockSums) {
    __shared__ int red[256];
    int i = blockIdx.x * 256 + threadIdx.x;
    red[threadIdx.x] = (i < N_NODES) ? degCount[i] : 0;
    __syncthreads();
    for (int off = 128; off > 0; off >>= 1) {
        if (threadIdx.x < off) red[threadIdx.x] += red[threadIdx.x + off];
        __syncthreads();
    }
    if (threadIdx.x == 0) blockSums[blockIdx.x] = red[0];
}

__global__ __launch_bounds__(256) void scan2_kernel(int* __restrict__ blockSums) {
    __shared__ int s[256];
    int t = threadIdx.x;
    int v = (t < NBLK_SCAN) ? blockSums[t] : 0;
    s[t] = v;
    __syncthreads();
    for (int off = 1; off < 256; off <<= 1) {
        int a = (t >= off) ? s[t - off] : 0;
        __syncthreads();
        s[t] += a;
        __syncthreads();
    }
    if (t < NBLK_SCAN) blockSums[t] = s[t] - v;   // exclusive prefix
}

__global__ __launch_bounds__(256) void scan3_kernel(int* __restrict__ degFill,
                                                    const int* __restrict__ blockSums,
                                                    int* __restrict__ rowPtr,
                                                    float* __restrict__ dinv) {
    __shared__ int s[256];
    int t = threadIdx.x;
    int i = blockIdx.x * 256 + t;
    int d = (i < N_NODES) ? degFill[i] : 0;
    s[t] = d;
    __syncthreads();
    for (int off = 1; off < 256; off <<= 1) {
        int a = (t >= off) ? s[t - off] : 0;
        __syncthreads();
        s[t] += a;
        __syncthreads();
    }
    int excl = s[t] - d + blockSums[blockIdx.x];
    if (i < N_NODES) {
        rowPtr[i]  = excl;
        degFill[i] = excl;
        dinv[i]    = 1.0f / sqrtf((float)(d + 1));
    }
    if (i == 0) rowPtr[N_NODES] = N_EDGES;
}

// ---------------------------------------------------------------------------
// K2: FUSED fill || gemm1 (both depend only on scan3; no LDS anywhere).
// Role interleave: blockIdx % 9 == 0 && blockIdx/9 < 391 -> gemm block
// (gemm_bid = blockIdx/9); else fill block (fill_bid = blockIdx - blockIdx/9 - 1).
// gemm1: g1 = (x @ W1) * dinv[row]; W read via coalesced 256B L2-hit loads
// (wave's 16 c4-groups = 16 contiguous float4s). 8 rows/thread for ILP.
// ---------------------------------------------------------------------------
#define FMA4(xs, w, a) { (a).x = fmaf((xs), (w).x, (a).x); \
                         (a).y = fmaf((xs), (w).y, (a).y); \
                         (a).z = fmaf((xs), (w).z, (a).z); \
                         (a).w = fmaf((xs), (w).w, (a).w); }

__global__ __launch_bounds__(256) void fill_gemm1_kernel(const int* __restrict__ ei,
                                                         int* __restrict__ fillPtr,
                                                         int* __restrict__ colIdx,
                                                         const float* __restrict__ x,
                                                         const float* __restrict__ W1,
                                                         const float* __restrict__ dinv,
                                                         float* __restrict__ out) {
    int div9 = blockIdx.x / 9;
    if ((blockIdx.x % 9) == 0 && div9 < GEMM1_BLOCKS) {
        // ---- gemm1 role ----
        const float4* W4 = (const float4*)W1;
        const int c4   = threadIdx.x & 15;
        const int rg   = threadIdx.x >> 4;
        const int row0 = div9 * 128 + rg * 8;

        const float4* ap[8];
#pragma unroll
        for (int r = 0; r < 8; ++r) {
            int rowc = min(row0 + r, N_NODES - 1);
            ap[r] = (const float4*)(x + (size_t)rowc * IN_CH);
        }

        float4 acc[8] = {};
        for (int kk = 0; kk < IN_CH / 4; ++kk) {
            float4 xv[8];
#pragma unroll
            for (int r = 0; r < 8; ++r) xv[r] = ap[r][kk];
            float4 w;
            w = W4[(4 * kk + 0) * 16 + c4];
#pragma unroll
            for (int r = 0; r < 8; ++r) FMA4(xv[r].x, w, acc[r]);
            w = W4[(4 * kk + 1) * 16 + c4];
#pragma unroll
            for (int r = 0; r < 8; ++r) FMA4(xv[r].y, w, acc[r]);
            w = W4[(4 * kk + 2) * 16 + c4];
#pragma unroll
            for (int r = 0; r < 8; ++r) FMA4(xv[r].z, w, acc[r]);
            w = W4[(4 * kk + 3) * 16 + c4];
#pragma unroll
            for (int r = 0; r < 8; ++r) FMA4(xv[r].w, w, acc[r]);
        }

#pragma unroll
        for (int r = 0; r < 8; ++r) {
            int row = row0 + r;
            if (row < N_NODES) {
                float dv = dinv[row];
                float4 o = acc[r];
                o.x *= dv; o.y *= dv; o.z *= dv; o.w *= dv;
                ((float4*)(out + (size_t)row * HID))[c4] = o;
            }
        }
        return;
    }
    // ---- fill role ----
    int fill_bid = blockIdx.x - div9 - ((blockIdx.x % 9) ? 1 : 0);
    if ((blockIdx.x % 9) == 0) fill_bid = blockIdx.x - div9;      // gemm slots exhausted
    int part = fill_bid & 7;
    int blk  = fill_bid >> 3;
    int lo   = part * 6250;
    int hi   = lo + 6250;
#pragma unroll
    for (int it = 0; it < 8; ++it) {
        int e = blk * 2048 + it * 256 + (int)threadIdx.x;
        if (e < N_EDGES) {
            int dst = ei[N_EDGES + e];
            if (dst >= lo && dst < hi) {
                int src = ei[e];
                int pos = atomicAdd(&fillPtr[dst], 1);
                colIdx[pos] = src;
            }
        }
    }
}

// ---------------------------------------------------------------------------
// K5: gemm2: g2 = (h1 @ W2) * dinv[row]  (standalone, LDS-staged)
// ---------------------------------------------------------------------------
template <int K>
__global__ __launch_bounds__(256) void gemm_kernel(const float* __restrict__ A,
                                                   const float* __restrict__ W,
                                                   const float* __restrict__ dinv,
                                                   float* __restrict__ out) {
    __shared__ float4 Ws[K * 16];
    for (int i = threadIdx.x; i < K * 16; i += 256)
        Ws[i] = ((const float4*)W)[i];
    __syncthreads();

    const int c4   = threadIdx.x & 15;
    const int rg   = threadIdx.x >> 4;
    const int row0 = blockIdx.x * 128 + rg * 8;

    const float4* ap[8];
#pragma unroll
    for (int r = 0; r < 8; ++r) {
        int rowc = min(row0 + r, N_NODES - 1);
        ap[r] = (const float4*)(A + (size_t)rowc * K);
    }

    float4 acc[8] = {};
    for (int kk = 0; kk < K / 4; ++kk) {
        float4 xv[8];
#pragma unroll
        for (int r = 0; r < 8; ++r) xv[r] = ap[r][kk];
        float4 w;
        w = Ws[(4 * kk + 0) * 16 + c4];
#pragma unroll
        for (int r = 0; r < 8; ++r) FMA4(xv[r].x, w, acc[r]);
        w = Ws[(4 * kk + 1) * 16 + c4];
#pragma unroll
        for (int r = 0; r < 8; ++r) FMA4(xv[r].y, w, acc[r]);
        w = Ws[(4 * kk + 2) * 16 + c4];
#pragma unroll
        for (int r = 0; r < 8; ++r) FMA4(xv[r].z, w, acc[r]);
        w = Ws[(4 * kk + 3) * 16 + c4];
#pragma unroll
        for (int r = 0; r < 8; ++r) FMA4(xv[r].w, w, acc[r]);
    }

#pragma unroll
    for (int r = 0; r < 8; ++r) {
        int row = row0 + r;
        if (row < N_NODES) {
            float dv = dinv[row];
            float4 o = acc[r];
            o.x *= dv; o.y *= dv; o.z *= dv; o.w *= dv;
            ((float4*)(out + (size_t)row * HID))[c4] = o;
        }
    }
}

// ---------------------------------------------------------------------------
// K4: layer-1 aggregation, float2 dual-row gather.
// Wave = 1 node. lane = (half, hl): half 0 handles even-indexed neighbors,
// half 1 odd-indexed; each lane loads float2 (channels 2hl,2hl+1). Halves
// combined with shfl_xor(32). 16 neighbors per batch iteration.
// ---------------------------------------------------------------------------
__global__ __launch_bounds__(256) void agg1_kernel(const float* __restrict__ g,
                                                   const float* __restrict__ dinv,
                                                   const int* __restrict__ rowPtr,
                                                   const int* __restrict__ colIdx,
                                                   const float* __restrict__ bias,
                                                   float* __restrict__ out) {
    int lane = threadIdx.x & 63;
    int half = lane >> 5;
    int hl   = lane & 31;
    int v = blockIdx.x * 4 + (threadIdx.x >> 6);
    if (v >= N_NODES) return;

    const float2* g2 = (const float2*)g;          // row stride = 32 float2
    float2 acc = {0.f, 0.f};
    if (half == 0) acc = g2[(size_t)v * 32 + hl]; // self term (once)

    int e0 = rowPtr[v];
    int e1 = rowPtr[v + 1];
    for (int e = e0; e < e1; e += 16) {
        int   u[8];
        float wsel[8];
#pragma unroll
        for (int k = 0; k < 8; ++k) {
            int ee  = e + 2 * k + half;
            int idx = min(ee, e1 - 1);
            u[k]    = colIdx[idx];
            wsel[k] = (ee < e1) ? 1.f : 0.f;
        }
#pragma unroll
        for (int k = 0; k < 8; ++k) {
            float2 a = g2[(size_t)u[k] * 32 + hl];
            acc.x = fmaf(wsel[k], a.x, acc.x);
            acc.y = fmaf(wsel[k], a.y, acc.y);
        }
    }
    acc.x += __shfl_xor(acc.x, 32);
    acc.y += __shfl_xor(acc.y, 32);

    float dv = dinv[v];
    float2 b = ((const float2*)bias)[hl];
    float2 r;
    r.x = fmaxf(dv * acc.x + b.x, 0.f);
    r.y = fmaxf(dv * acc.y + b.y, 0.f);
    if (half == 0) ((float2*)(out + (size_t)v * HID))[hl] = r;
}

// ---------------------------------------------------------------------------
// K6: layer-2 aggregation + replicated pool atomics, float2 dual-row gather.
// After combine every lane has the full float2; half 0 adds ch 2hl, half 1
// adds ch 2hl+1 -> one atomic per lane, 64 channels covered once.
// ---------------------------------------------------------------------------
__global__ __launch_bounds__(256) void agg2pool_kernel(const float* __restrict__ g,
                                                       const float* __restrict__ dinv,
                                                       const int* __restrict__ rowPtr,
                                                       const int* __restrict__ colIdx,
                                                       const float* __restrict__ bias,
                                                       const int* __restrict__ batch,
                                                       float* __restrict__ pooledSum) {
    int lane = threadIdx.x & 63;
    int half = lane >> 5;
    int hl   = lane & 31;
    int v = blockIdx.x * 4 + (threadIdx.x >> 6);
    if (v >= N_NODES) return;

    const float2* g2 = (const float2*)g;
    float2 acc = {0.f, 0.f};
    if (half == 0) acc = g2[(size_t)v * 32 + hl];

    int e0 = rowPtr[v];
    int e1 = rowPtr[v + 1];
    for (int e = e0; e < e1; e += 16) {
        int   u[8];
        float wsel[8];
#pragma unroll
        for (int k = 0; k < 8; ++k) {
            int ee  = e + 2 * k + half;
            int idx = min(ee, e1 - 1);
            u[k]    = colIdx[idx];
            wsel[k] = (ee < e1) ? 1.f : 0.f;
        }
#pragma unroll
        for (int k = 0; k < 8; ++k) {
            float2 a = g2[(size_t)u[k] * 32 + hl];
            acc.x = fmaf(wsel[k], a.x, acc.x);
            acc.y = fmaf(wsel[k], a.y, acc.y);
        }
    }
    acc.x += __shfl_xor(acc.x, 32);
    acc.y += __shfl_xor(acc.y, 32);

    float dv = dinv[v];
    float2 b = ((const float2*)bias)[hl];
    float rx = fmaxf(dv * acc.x + b.x, 0.f);
    float ry = fmaxf(dv * acc.y + b.y, 0.f);

    int gid = batch[v];                           // wave-uniform
    int rep = blockIdx.x & (NREP - 1);
    atomicAdd(&pooledSum[(size_t)rep * N_GRAPHS * HID + gid * HID + 2 * hl + half],
              half ? ry : rx);
}

// ---------------------------------------------------------------------------
// K7: finalize. Sums 32 replicas, divides by count, head via shuffle reduce.
// d_out layout: [ out (64x2) | pooled (64x64) ]
// ---------------------------------------------------------------------------
__global__ __launch_bounds__(64) void pool2_kernel(const float* __restrict__ pooledSum,
                                                   const int* __restrict__ batch,
                                                   const float* __restrict__ Wl,
                                                   const float* __restrict__ bl,
                                                   float* __restrict__ dout) {
    int g    = blockIdx.x;
    int lane = threadIdx.x;

    int lo0 = 0, hi = N_NODES;
    while (lo0 < hi) { int mid = (lo0 + hi) >> 1; if (batch[mid] < g) lo0 = mid + 1; else hi = mid; }
    int lo1 = lo0; hi = N_NODES;
    while (lo1 < hi) { int mid = (lo1 + hi) >> 1; if (batch[mid] < g + 1) lo1 = mid + 1; else hi = mid; }
    float cnt = (float)(lo1 - lo0);

    float s = 0.f;
#pragma unroll
    for (int rep = 0; rep < NREP; ++rep)
        s += pooledSum[(size_t)rep * N_GRAPHS * HID + g * HID + lane];

    float p = s / fmaxf(cnt, 1.0f);
    dout[N_GRAPHS * N_CLASSES + g * HID + lane] = p;

    float p0 = p * Wl[lane * N_CLASSES + 0];
    float p1 = p * Wl[lane * N_CLASSES + 1];
#pragma unroll
    for (int off = 32; off > 0; off >>= 1) {
        p0 += __shfl_down(p0, off, 64);
        p1 += __shfl_down(p1, off, 64);
    }
    if (lane == 0) {
        dout[g * N_CLASSES + 0] = p0 + bl[0];
        dout[g * N_CLASSES + 1] = p1 + bl[1];
    }
}

// ---------------------------------------------------------------------------
extern "C" void kernel_launch(void* const* d_in, const int* in_sizes, int n_in,
                              void* d_out, int out_size, void* d_ws, size_t ws_size,
                              hipStream_t stream) {
    const float* x     = (const float*)d_in[0];
    const int*   ei    = (const int*)d_in[1];    // int32 on device
    const int*   batch = (const int*)d_in[2];    // int32 on device
    const float* W1    = (const float*)d_in[3];
    const float* b1    = (const float*)d_in[4];
    const float* W2    = (const float*)d_in[5];
    const float* b2    = (const float*)d_in[6];
    const float* Wl    = (const float*)d_in[7];
    const float* bl    = (const float*)d_in[8];
    float* out = (float*)d_out;

    char* ws = (char*)d_ws;
    size_t off = 0;
    auto alloc = [&](size_t bytes) -> void* {
        void* p = ws + off;
        off += (bytes + 255) & ~(size_t)255;
        return p;
    };
    int*   degFill   = (int*)  alloc((size_t)N_NODES * 4);        // counts -> fillPtr
    int*   rowPtr    = (int*)  alloc((size_t)(N_NODES + 1) * 4);
    float* dinv      = (float*)alloc((size_t)N_NODES * 4);
    int*   blockSums = (int*)  alloc((size_t)NBLK_SCAN * 4);
    float* pooledSum = (float*)alloc((size_t)NREP * N_GRAPHS * HID * 4);  // 512 KB
    int*   colIdx    = (int*)  alloc((size_t)N_EDGES * 4);
    float* bufA      = (float*)alloc((size_t)N_NODES * HID * 4);  // g1, then g2
    float* bufB      = (float*)alloc((size_t)N_NODES * HID * 4);  // h1

    hipMemsetAsync(degFill, 0, (size_t)N_NODES * 4, stream);
    hipMemsetAsync(pooledSum, 0, (size_t)NREP * N_GRAPHS * HID * 4, stream);

    deg_kernel  <<<DEG_BLOCKS, 256, 0, stream>>>(ei, degFill);
    scan1_kernel<<<NBLK_SCAN, 256, 0, stream>>>(degFill, blockSums);
    scan2_kernel<<<1, 256, 0, stream>>>(blockSums);
    scan3_kernel<<<NBLK_SCAN, 256, 0, stream>>>(degFill, blockSums, rowPtr, dinv);

    // fused: fill (3128 blocks) || gemm1 LDS-free (391 blocks), interleaved
    fill_gemm1_kernel<<<DEG_BLOCKS + GEMM1_BLOCKS, 256, 0, stream>>>(
        ei, degFill, colIdx, x, W1, dinv, bufA);

    // layer 1 aggregation
    agg1_kernel<<<N_NODES / 4, 256, 0, stream>>>(bufA, dinv, rowPtr, colIdx, b1, bufB);

    // layer 2
    gemm_kernel<HID><<<GEMM1_BLOCKS, 256, 0, stream>>>(bufB, W2, dinv, bufA);
    agg2pool_kernel <<<N_NODES / 4, 256, 0, stream>>>(bufA, dinv, rowPtr, colIdx, b2, batch, pooledSum);

    // finalize pool + head
    pool2_kernel<<<N_GRAPHS, 64, 0, stream>>>(pooledSum, batch, Wl, bl, out);
}